// Round 12
// baseline (256.324 us; speedup 1.0000x reference)
//
#include <hip/hip_runtime.h>

typedef __attribute__((ext_vector_type(8))) short bf16x8_t;
typedef __attribute__((ext_vector_type(4))) float f32x4_t;
typedef __attribute__((ext_vector_type(4))) unsigned u32x4_t;
typedef unsigned int u32;

#define BATCH 4
#define CH 64
#define HIN 256
#define WIN 512
#define NDISP 65
#define TY 2
#define TX 254
#define NSTEP 8

// ---- workspace layout (floats unless noted) ----
#define CS0_OFF 0
#define CQ0_OFF  524288
#define CS1_OFF 1048576
#define CQ1_OFF 1572864
#define SB0_OFF 2097152
#define LB0_OFF 2621440
#define SB1_OFF 3145728
#define LB1_OFF 3809280
#define STATS_FLOATS 4472832UL
#define X1T_U16 33554432UL     // u16 offset of x1T within bf16T region
#define WS_NEED_BYTES (STATS_FLOATS*4UL + 2UL*X1T_U16*2UL)

// ---- DMA main kernel LDS: 2 x 40 KB staging buffers, Q/aux aliased ----
#define BUFB 40960             // one staging buffer: x0 16KB + x1 24KB
#define X0PARB 8192            // 128 lines x 64B per parity
#define X1SEC 16384
#define X1PARB 12288           // 192 lines x 64B per parity (12 groups)
#define SM_S0X 66824
#define SM_L0X 67848
#define SM_S1X 68872
#define SM_L1X 70408
#define SMEMB 81920            // exactly 80 KB -> 2 blocks/CU

// ---- fallback monolith LDS (R9) ----
#define FB_BUF 40960
#define FB_X0 0
#define FB_X0PS 8192
#define FB_X1 16384
#define FB_X1PS 12288
#define FB_QB 0
#define FB_S0X 66824
#define FB_L0X 67848
#define FB_S1X 68872
#define FB_L1X 70408
#define FB_SMEM 81920

#define WAITVM(n) asm volatile("s_waitcnt vmcnt(" #n ")" ::: "memory")

__device__ __forceinline__ void gl16(const void* g, void* l) {
  __builtin_amdgcn_global_load_lds(
      (const __attribute__((address_space(1))) u32*)g,
      (__attribute__((address_space(3))) u32*)l, 16, 0, 0);
}

__device__ __forceinline__ int fixog(int og, int xb, int ogmax) {
  const int xmin = xb + 32 * og;
  if (xmin + 30 < 0 || xmin >= WIN) {
    int f = (31 - xb) >> 5;
    f = f < 0 ? 0 : f;
    og = f > ogmax ? ogmax : f;
  }
  return og;
}

// ---------------- pass A: channel column sums + bf16 transpose-pack ----------------
__global__ __launch_bounds__(512)
void colsum_kernel(const float* __restrict__ x0, const float* __restrict__ x1,
                   float* __restrict__ ws, int write_t) {
  const int y = blockIdx.x, b = blockIdx.y, x = threadIdx.x;
  const size_t plane = (size_t)HIN * WIN;
  const float* p0 = x0 + (size_t)b * CH * plane + (size_t)y * WIN + x;
  const float* p1 = x1 + (size_t)b * CH * plane + (size_t)y * WIN + x;
  unsigned short* t0 = (unsigned short*)(ws + STATS_FLOATS);
  unsigned short* t1 = t0 + X1T_U16;
  float s0 = 0.f, q0 = 0.f, s1 = 0.f, q1 = 0.f;
  for (int cc = 0; cc < 2; ++cc) {
    u32 w0[16], w1[16];
#pragma unroll
    for (int j = 0; j < 16; ++j) {
      const float a0 = p0[(size_t)(cc * 32 + 2 * j) * plane];
      const float a1 = p0[(size_t)(cc * 32 + 2 * j + 1) * plane];
      const float c0 = p1[(size_t)(cc * 32 + 2 * j) * plane];
      const float c1 = p1[(size_t)(cc * 32 + 2 * j + 1) * plane];
      s0 += a0 + a1; q0 += a0 * a0 + a1 * a1;
      s1 += c0 + c1; q1 += c0 * c0 + c1 * c1;
      asm("v_cvt_pk_bf16_f32 %0, %1, %2" : "=v"(w0[j]) : "v"(a0), "v"(a1));
      asm("v_cvt_pk_bf16_f32 %0, %1, %2" : "=v"(w1[j]) : "v"(c0), "v"(c1));
    }
    if (write_t) {
      const size_t o = ((((size_t)b * 2 + cc) * HIN + y) * WIN + x) * 32;
#pragma unroll
      for (int g = 0; g < 4; ++g) {
        u32x4_t v0 = {w0[4*g], w0[4*g+1], w0[4*g+2], w0[4*g+3]};
        u32x4_t v1 = {w1[4*g], w1[4*g+1], w1[4*g+2], w1[4*g+3]};
        *(u32x4_t*)(t0 + o + 8 * g) = v0;
        *(u32x4_t*)(t1 + o + 8 * g) = v1;
      }
    }
  }
  const size_t o = ((size_t)b * HIN + y) * WIN + x;
  ws[CS0_OFF + o] = s0; ws[CQ0_OFF + o] = q0;
  ws[CS1_OFF + o] = s1; ws[CQ1_OFF + o] = q1;
}

// ---------------- pass B: 3x3 boxed patch stats + norms ----------------
__global__ __launch_bounds__(512)
void boxnorm_kernel(float* __restrict__ ws) {
  const int y = blockIdx.x, b = blockIdx.y;
  const int tid = threadIdx.x;
  const float invn = 1.f / 576.f;
  const int ylo = (y > 0) ? y - 1 : 0;
  const int yhi = (y < HIN - 1) ? y + 1 : HIN - 1;
  {
    const int x = tid;
    float s = 0.f, q = 0.f;
    for (int yy = ylo; yy <= yhi; ++yy) {
      const float* rs = ws + CS0_OFF + ((size_t)b * HIN + yy) * WIN;
      const float* rq = ws + CQ0_OFF + ((size_t)b * HIN + yy) * WIN;
      const int xlo = (x > 0) ? x - 1 : 0;
      const int xhi = (x < WIN - 1) ? x + 1 : WIN - 1;
      for (int xx = xlo; xx <= xhi; ++xx) { s += rs[xx]; q += rq[xx]; }
    }
    const size_t o = ((size_t)b * HIN + y) * WIN + x;
    ws[SB0_OFF + o] = s;
    ws[LB0_OFF + o] = sqrtf(fmaxf(q - s * s * invn, 0.f));
  }
  for (int i = tid; i < 648; i += 512) {
    const int v = i - 66;
    float s = 0.f, q = 0.f;
    const int xlo = (v - 1 > 0) ? v - 1 : 0;
    const int xhi = (v + 1 < WIN - 1) ? v + 1 : WIN - 1;
    if (v + 1 >= 0 && v - 1 < WIN) {
      for (int yy = ylo; yy <= yhi; ++yy) {
        const float* rs = ws + CS1_OFF + ((size_t)b * HIN + yy) * WIN;
        const float* rq = ws + CQ1_OFF + ((size_t)b * HIN + yy) * WIN;
        for (int xx = xlo; xx <= xhi; ++xx) { s += rs[xx]; q += rq[xx]; }
      }
    }
    const size_t o = ((size_t)b * HIN + y) * 648 + i;
    ws[SB1_OFF + o] = s;
    ws[LB1_OFF + o] = sqrtf(fmaxf(q - s * s * invn, 0.f));
  }
}

// ---------------- main: DMA-staged banded MFMA, depth-2 pipeline, 2 blocks/CU ----------------
__global__ __launch_bounds__(1024, 8)
void corrzn_dma_kernel(const float* __restrict__ ws, float* __restrict__ out) {
  __shared__ __align__(16) char smem[SMEMB];

  const int tid  = threadIdx.x;
  const int lane = tid & 63;
  const int wv   = tid >> 6;      // 0..15
  const int p    = wv & 1;        // compute parity
  const int ch   = wv >> 1;       // M-chunk 0..7
  const int lm = lane & 15;
  const int lk = lane >> 4;

  // bijective XCD-chunk swizzle over the 1536-block grid (1536 % 8 == 0)
  const int flat = blockIdx.x + 3 * (blockIdx.y + 128 * blockIdx.z);
  const int sw = (flat & 7) * 192 + (flat >> 3);
  const int bx = sw % 3;
  const int tmp = sw / 3;
  const int by = tmp & 127;
  const int b  = tmp >> 7;

  const int x0blk = bx * TX;
  const int y0    = by * TY;

  const unsigned short* t0 = (const unsigned short*)(ws + STATS_FLOATS);
  const unsigned short* t1 = t0 + X1T_U16;

  // per-wave DMA op params (step-invariant)
  const int pa  = wv >> 3, ga0 = wv & 7;         // x0: 8 groups x 16 lines per parity
  const int xbA = x0blk - 1 + pa;
  const int gaA = fixog(ga0, xbA, 7);
  const int pb  = (wv >= 12) ? 1 : 0;            // x1 B-op: 12 groups parity0 + 4 of parity1
  const int xbB = x0blk - 65 + pb;
  const int gaB = fixog(wv - 12 * pb, xbB, 11);
  const int xbC = x0blk - 64;                    // x1 C-op: parity1 groups 4..11 (wv<8)
  const int gaC = fixog(wv + 4, xbC, 11);
  const bool ops3 = (wv < 8);

  f32x4_t acc[TY][5];
#pragma unroll
  for (int t = 0; t < TY; ++t)
#pragma unroll
    for (int T = 0; T < 5; ++T)
      acc[t][T] = (f32x4_t){0.f, 0.f, 0.f, 0.f};

  auto issue = [&](int k) {
    const int r = k >> 1, cc = k & 1;
    int orow = y0 + r - 1;
    orow = orow < 0 ? 0 : (orow > HIN - 1 ? HIN - 1 : orow);
    char* bb = smem + (k & 1) * BUFB;
    const size_t rowo = ((((size_t)b * 2 + cc) * HIN + orow) * (size_t)WIN) * 32;
    const unsigned short* r0 = t0 + rowo;
    const unsigned short* r1 = t1 + rowo;
    {
      const int line = 16 * gaA + (lane >> 2);
      const int xg = xbA + 2 * line;
      const int ss = (lane & 3) ^ ((line >> 1) & 3);
      if (xg >= 0 && xg < WIN)
        gl16(r0 + (size_t)xg * 32 + ss * 8, bb + pa * X0PARB + gaA * 1024);
    }
    {
      const int line = 16 * gaB + (lane >> 2);
      const int xg = xbB + 2 * line;
      const int ss = (lane & 3) ^ ((line >> 1) & 3);
      if (xg >= 0 && xg < WIN)
        gl16(r1 + (size_t)xg * 32 + ss * 8, bb + X1SEC + pb * X1PARB + gaB * 1024);
    }
    if (ops3) {
      const int line = 16 * gaC + (lane >> 2);
      const int xg = xbC + 2 * line;
      const int ss = (lane & 3) ^ ((line >> 1) & 3);
      if (xg >= 0 && xg < WIN)
        gl16(r1 + (size_t)xg * 32 + ss * 8, bb + X1SEC + X1PARB + gaC * 1024);
    }
  };

  // zero-init staging so masked (out-of-image) cells read as 0 forever
  {
    u32x4_t z = {0u, 0u, 0u, 0u};
    for (int i = tid; i < 2 * BUFB / 16; i += 1024)
      ((u32x4_t*)smem)[i] = z;
  }
  __syncthreads();

  issue(0); issue(1);
  if (ops3) { WAITVM(3); } else { WAITVM(2); }   // step-0 loads done
  __builtin_amdgcn_s_barrier();
  asm volatile("" ::: "memory");

#pragma unroll
  for (int k = 0; k < NSTEP; ++k) {
    const int r = k >> 1;
    const int orow = y0 + r - 1;
    if (orow >= 0 && orow < HIN) {
      char* bb = smem + (k & 1) * BUFB;
      bf16x8_t afr, bfr[5];
      {
        const int pos = 16 * ch + lm;
        const int slot = lk ^ ((pos >> 1) & 3);
        afr = *(const bf16x8_t*)(bb + p * X0PARB + pos * 64 + slot * 16);
      }
#pragma unroll
      for (int T = 0; T < 5; ++T) {
        const int pos = 16 * (ch + T) + lm;
        const int slot = lk ^ ((pos >> 1) & 3);
        bfr[T] = *(const bf16x8_t*)(bb + X1SEC + p * X1PARB + pos * 64 + slot * 16);
      }
#pragma unroll
      for (int t = 0; t < TY; ++t) {
        if (t >= r - 2 && t <= r) {
#pragma unroll
          for (int T = 0; T < 5; ++T)
            acc[t][T] = __builtin_amdgcn_mfma_f32_16x16x32_bf16(
                afr, bfr[T], acc[t][T], 0, 0, 0);
        }
      }
    }
    asm volatile("s_waitcnt lgkmcnt(0)" ::: "memory");
    __builtin_amdgcn_s_barrier();
    asm volatile("" ::: "memory");
    if (k == NSTEP - 1) break;
    if (k + 2 < NSTEP) {
      issue(k + 2);                              // reuses buffer (k&1), just freed
      if (ops3) { WAITVM(3); } else { WAITVM(2); }  // step k+1 loads done
    } else {
      WAITVM(0);                                 // drain for final step
    }
    __builtin_amdgcn_s_barrier();
    asm volatile("" ::: "memory");
  }

  // ============ epilogue: full-Q dump per row (aliases staging), rcp-normalize ============
  float* Q   = (float*)(smem);
  float* s0x = (float*)(smem + SM_S0X);
  float* l0x = (float*)(smem + SM_L0X);
  float* s1x = (float*)(smem + SM_S1X);
  float* l1x = (float*)(smem + SM_L1X);
  const float invn = 1.f / 576.f;

#pragma unroll
  for (int t = 0; t < TY; ++t) {
    const int row = y0 + t;
    __syncthreads();
    for (int i = tid; i < 254; i += 1024) {
      const int x = x0blk + i;
      const size_t o = ((size_t)b * HIN + row) * WIN + x;
      s0x[i] = (x < WIN) ? ws[SB0_OFF + o] : 0.f;
      l0x[i] = (x < WIN) ? ws[LB0_OFF + o] : 0.f;
    }
    for (int j2 = tid; j2 < 382; j2 += 1024) {
      const int idx = x0blk + 2 + j2;
      const size_t o = ((size_t)b * HIN + row) * 648 + idx;
      s1x[j2] = (idx < 648) ? ws[SB1_OFF + o] : 0.f;
      l1x[j2] = (idx < 648) ? ws[LB1_OFF + o] : 0.f;
    }
#pragma unroll
    for (int T = 0; T < 5; ++T)
#pragma unroll
      for (int q = 0; q < 4; ++q) {
        const int mg = 16 * ch + lk * 4 + q;
        const int di = 16 * T + lm - 4 * lk - q;
        if (di >= 0 && di <= 64)
          Q[di * 257 + 2 * mg + p] = acc[t][T][q];
      }
    __syncthreads();
    // output: fixed xl pair per thread, walk di (no divisions, float2 stores)
    const int xl = 2 * (tid & 127);
    const int di0 = tid >> 7;                    // 0..7
    if (xl < TX && x0blk + xl + 1 < WIN) {
      for (int di = di0; di < NDISP; di += 8) {
        const float qa0 = Q[di * 257 + xl];
        const float qa1 = Q[di * 257 + xl + 1];
        const float qa2 = Q[di * 257 + xl + 2];
        const float qa3 = Q[di * 257 + xl + 3];
        const int j = xl + 2 * di;
        const float n0 = (qa0 + qa1 + qa2) - s0x[xl] * s1x[j] * invn;
        const float d0 = l0x[xl] * l1x[j] + 1e-8f;
        const float n1 = (qa1 + qa2 + qa3) - s0x[xl + 1] * s1x[j + 1] * invn;
        const float d1 = l0x[xl + 1] * l1x[j + 1] + 1e-8f;
        float r0, r1;
        asm("v_rcp_f32 %0, %1" : "=v"(r0) : "v"(d0));
        asm("v_rcp_f32 %0, %1" : "=v"(r1) : "v"(d1));
        float2 o2; o2.x = n0 * r0; o2.y = n1 * r1;
        *(float2*)(out + (((size_t)b * NDISP + di) * HIN + row) * WIN + x0blk + xl) = o2;
      }
    }
  }
}

// ---------------- fallback monolith (R9, 211us) ----------------
__global__ __launch_bounds__(512, 2)
void corrzn_kernel(const float* __restrict__ x0, const float* __restrict__ x1,
                   const float* __restrict__ ws, float* __restrict__ out) {
  __shared__ __align__(16) char smem[FB_SMEM];
  const int tid  = threadIdx.x;
  const int lane = tid & 63;
  const int wv   = tid >> 6;
  const int p    = wv & 1;
  const int chunk0 = 2 * (wv >> 1);
  const int lm = lane & 15;
  const int lk = lane >> 4;
  const int t5  = tid & 31;
  const int cpx = tid >> 5;
  const int x0blk = blockIdx.x * TX;
  const int y0    = blockIdx.y * TY;
  const int b     = blockIdx.z;
  const size_t plane = (size_t)HIN * WIN;
  const float* x0b = x0 + (size_t)b * CH * plane;
  const float* x1b = x1 + (size_t)b * CH * plane;

  f32x4_t acc[TY][2][5];
#pragma unroll
  for (int t = 0; t < TY; ++t)
#pragma unroll
    for (int mc = 0; mc < 2; ++mc)
#pragma unroll
      for (int T = 0; T < 5; ++T)
        acc[t][mc][T] = (f32x4_t){0.f, 0.f, 0.f, 0.f};

  float2 R0[12], R1[12];
  auto prefetch = [&](int k) {
    const int r = k >> 1, cc = k & 1;
    const int orow = y0 + r - 1;
    const bool rowok = (orow >= 0) && (orow < HIN);
    const int ro = rowok ? orow : 0;
    const float* s0p = x0b + (size_t)(cc * 32 + 2 * cpx) * plane + (size_t)ro * WIN;
    const float* s1p = x1b + (size_t)(cc * 32 + 2 * cpx) * plane + (size_t)ro * WIN;
#pragma unroll
    for (int it = 0; it < 5; ++it) {
      const int wp = 32 * it + t5;
      const int xg = x0blk - 2 + 2 * wp;
      float2 a = {0.f, 0.f}, c = {0.f, 0.f};
      if (rowok && wp <= 128 && xg >= 0 && xg < WIN - 1) {
        a = *(const float2*)(s0p + xg);
        c = *(const float2*)(s0p + plane + xg);
      }
      R0[it] = a; R1[it] = c;
    }
#pragma unroll
    for (int it = 0; it < 7; ++it) {
      const int wp = 32 * it + t5;
      const int xg = x0blk - 66 + 2 * wp;
      float2 a = {0.f, 0.f}, c = {0.f, 0.f};
      if (rowok && wp <= 192 && xg >= 0 && xg < WIN - 1) {
        a = *(const float2*)(s1p + xg);
        c = *(const float2*)(s1p + plane + xg);
      }
      R0[5 + it] = a; R1[5 + it] = c;
    }
  };
  auto wstage = [&](int bb) {
#pragma unroll
    for (int it = 0; it < 12; ++it) {
      const bool isx1 = it >= 5;
      const int wp = 32 * (isx1 ? it - 5 : it) + t5;
      const int base = bb + (isx1 ? FB_X1 : FB_X0);
      const int ps   = isx1 ? FB_X1PS : FB_X0PS;
      const int pmax = isx1 ? 192 : 128;
      u32 pkA, pkB;
      asm("v_cvt_pk_bf16_f32 %0, %1, %2" : "=v"(pkA) : "v"(R0[it].x), "v"(R1[it].x));
      asm("v_cvt_pk_bf16_f32 %0, %1, %2" : "=v"(pkB) : "v"(R0[it].y), "v"(R1[it].y));
      if (wp >= 1 && wp <= pmax) {
        const int pos = wp - 1;
        const int slot = (cpx >> 2) ^ ((pos >> 1) & 3);
        *(u32*)(smem + base + ps + pos * 64 + slot * 16 + (cpx & 3) * 4) = pkA;
      }
      if (wp <= pmax - 1) {
        const int pos = wp;
        const int slot = (cpx >> 2) ^ ((pos >> 1) & 3);
        *(u32*)(smem + base + pos * 64 + slot * 16 + (cpx & 3) * 4) = pkB;
      }
    }
  };

  prefetch(0); wstage(0); prefetch(1);
  asm volatile("s_waitcnt lgkmcnt(0)" ::: "memory");
  __builtin_amdgcn_s_barrier();
  asm volatile("" ::: "memory");

#pragma unroll
  for (int k = 0; k < 12; ++k) {
    const int r = k >> 1;
    const int cur = (k & 1) * FB_BUF;
    bf16x8_t afr[2], bfr[6];
#pragma unroll
    for (int mc = 0; mc < 2; ++mc) {
      const int pos = 16 * (chunk0 + mc) + lm;
      const int slot = lk ^ ((pos >> 1) & 3);
      afr[mc] = *(const bf16x8_t*)(smem + cur + FB_X0 + p * FB_X0PS + pos * 64 + slot * 16);
    }
#pragma unroll
    for (int u = 0; u < 6; ++u) {
      const int pos = 16 * (chunk0 + u) + lm;
      const int slot = lk ^ ((pos >> 1) & 3);
      bfr[u] = *(const bf16x8_t*)(smem + cur + FB_X1 + p * FB_X1PS + pos * 64 + slot * 16);
    }
#pragma unroll
    for (int t = 0; t < TY; ++t) {
      if (t >= r - 2 && t <= r) {
#pragma unroll
        for (int mc = 0; mc < 2; ++mc)
#pragma unroll
          for (int T = 0; T < 5; ++T)
            acc[t][mc][T] = __builtin_amdgcn_mfma_f32_16x16x32_bf16(
                afr[mc], bfr[mc + T], acc[t][mc][T], 0, 0, 0);
      }
    }
    if (k < 11) {
      wstage(((k + 1) & 1) * FB_BUF);
      if (k + 2 < 12) prefetch(k + 2);
      asm volatile("s_waitcnt lgkmcnt(0)" ::: "memory");
      __builtin_amdgcn_s_barrier();
      asm volatile("" ::: "memory");
    }
  }

  float* Q   = (float*)(smem + FB_QB);
  float* s0x = (float*)(smem + FB_S0X);
  float* l0x = (float*)(smem + FB_L0X);
  float* s1x = (float*)(smem + FB_S1X);
  float* l1x = (float*)(smem + FB_L1X);
  const float invn = 1.f / 576.f;
#pragma unroll
  for (int t = 0; t < TY; ++t) {
    const int row = y0 + t;
    __syncthreads();
    for (int i = tid; i < 254; i += 512) {
      const int x = x0blk + i;
      const size_t o = ((size_t)b * HIN + row) * WIN + x;
      s0x[i] = (x < WIN) ? ws[SB0_OFF + o] : 0.f;
      l0x[i] = (x < WIN) ? ws[LB0_OFF + o] : 0.f;
    }
    for (int j2 = tid; j2 < 382; j2 += 512) {
      const int idx = x0blk + 2 + j2;
      const size_t o = ((size_t)b * HIN + row) * 648 + idx;
      s1x[j2] = (idx < 648) ? ws[SB1_OFF + o] : 0.f;
      l1x[j2] = (idx < 648) ? ws[LB1_OFF + o] : 0.f;
    }
#pragma unroll
    for (int mc = 0; mc < 2; ++mc)
#pragma unroll
      for (int T = 0; T < 5; ++T)
#pragma unroll
        for (int q = 0; q < 4; ++q) {
          const int mg = 16 * (chunk0 + mc) + lk * 4 + q;
          const int di = 16 * T + lm - 4 * lk - q;
          if (di >= 0 && di <= 64)
            Q[di * 257 + 2 * mg + p] = acc[t][mc][T][q];
        }
    __syncthreads();
    for (int oi = tid; oi < NDISP * TX; oi += 512) {
      const int di = oi / TX;
      const int xl = oi - di * TX;
      const int x = x0blk + xl;
      if (x < WIN) {
        const float q3 = Q[di * 257 + xl] + Q[di * 257 + xl + 1] + Q[di * 257 + xl + 2];
        const int j = xl + 2 * di;
        const float numer = q3 - s0x[xl] * s1x[j] * invn;
        const float den = l0x[xl] * l1x[j] + 1e-8f;
        float rd;
        asm("v_rcp_f32 %0, %1" : "=v"(rd) : "v"(den));
        out[(((size_t)b * NDISP + di) * HIN + row) * WIN + x] = numer * rd;
      }
    }
  }
}

extern "C" void kernel_launch(void* const* d_in, const int* in_sizes, int n_in,
                              void* d_out, int out_size, void* d_ws, size_t ws_size,
                              hipStream_t stream) {
  const float* x0 = (const float*)d_in[0];
  const float* x1 = (const float*)d_in[1];
  float* out = (float*)d_out;
  float* wsf = (float*)d_ws;
  const int use_dma = (ws_size >= WS_NEED_BYTES) ? 1 : 0;

  colsum_kernel<<<dim3(HIN, BATCH), 512, 0, stream>>>(x0, x1, wsf, use_dma);
  boxnorm_kernel<<<dim3(HIN, BATCH), 512, 0, stream>>>(wsf);
  if (use_dma) {
    corrzn_dma_kernel<<<dim3(3, HIN / TY, BATCH), 1024, 0, stream>>>(wsf, out);
  } else {
    corrzn_kernel<<<dim3(3, HIN / TY, BATCH), 512, 0, stream>>>(x0, x1, wsf, out);
  }
}

// Round 13
// 207.158 us; speedup vs baseline: 1.2373x; 1.2373x over previous
//
#include <hip/hip_runtime.h>

typedef __attribute__((ext_vector_type(8))) short bf16x8_t;
typedef __attribute__((ext_vector_type(4))) float f32x4_t;
typedef __attribute__((ext_vector_type(4))) unsigned u32x4_t;
typedef unsigned int u32;

#define BATCH 4
#define CH 64
#define HIN 256
#define WIN 512
#define NDISP 65
#define TY 2
#define TX 254

// ---- workspace layout (floats unless noted) ----
#define CS0_OFF 0
#define CQ0_OFF  524288
#define CS1_OFF 1048576
#define CQ1_OFF 1572864
#define SB0_OFF 2097152
#define LB0_OFF 2621440
#define SB1_OFF 3145728
#define LB1_OFF 3809280
#define STATS_FLOATS 4472832UL
#define X1T_U16 33554432UL     // u16 offset of x1T within bf16T region
#define WS_NEED_BYTES (STATS_FLOATS*4UL + 2UL*X1T_U16*2UL)

// ---- DMA main kernel LDS: 2 x 40 KB staging buffers, Q/aux aliased ----
#define BUFB 40960             // one staging buffer: x0 16KB + x1 24KB
#define X0PARB 8192            // 128 lines x 64B per parity
#define X1SEC 16384
#define X1PARB 12288           // 192 lines x 64B per parity (12 groups)
#define SM_S0X 66824
#define SM_L0X 67848
#define SM_S1X 68872
#define SM_L1X 70408
#define SMEMB 81920            // exactly 80 KB -> 2 blocks/CU

// ---- fallback monolith LDS (R9) ----
#define FB_BUF 40960
#define FB_X0 0
#define FB_X0PS 8192
#define FB_X1 16384
#define FB_X1PS 12288
#define FB_QB 0
#define FB_S0X 66824
#define FB_L0X 67848
#define FB_S1X 68872
#define FB_L1X 70408
#define FB_SMEM 81920

#define WAITVM(n) asm volatile("s_waitcnt vmcnt(" #n ")" ::: "memory")

__device__ __forceinline__ void gl16(const void* g, void* l) {
  __builtin_amdgcn_global_load_lds(
      (const __attribute__((address_space(1))) u32*)g,
      (__attribute__((address_space(3))) u32*)l, 16, 0, 0);
}

__device__ __forceinline__ int fixog(int og, int xb, int ogmax) {
  const int xmin = xb + 32 * og;
  if (xmin + 30 < 0 || xmin >= WIN) {
    int f = (31 - xb) >> 5;
    f = f < 0 ? 0 : f;
    og = f > ogmax ? ogmax : f;
  }
  return og;
}

// ---------------- pass A: channel column sums + bf16 transpose-pack ----------------
__global__ __launch_bounds__(512)
void colsum_kernel(const float* __restrict__ x0, const float* __restrict__ x1,
                   float* __restrict__ ws, int write_t) {
  const int y = blockIdx.x, b = blockIdx.y, x = threadIdx.x;
  const size_t plane = (size_t)HIN * WIN;
  const float* p0 = x0 + (size_t)b * CH * plane + (size_t)y * WIN + x;
  const float* p1 = x1 + (size_t)b * CH * plane + (size_t)y * WIN + x;
  unsigned short* t0 = (unsigned short*)(ws + STATS_FLOATS);
  unsigned short* t1 = t0 + X1T_U16;
  float s0 = 0.f, q0 = 0.f, s1 = 0.f, q1 = 0.f;
  for (int cc = 0; cc < 2; ++cc) {
    u32 w0[16], w1[16];
#pragma unroll
    for (int j = 0; j < 16; ++j) {
      const float a0 = p0[(size_t)(cc * 32 + 2 * j) * plane];
      const float a1 = p0[(size_t)(cc * 32 + 2 * j + 1) * plane];
      const float c0 = p1[(size_t)(cc * 32 + 2 * j) * plane];
      const float c1 = p1[(size_t)(cc * 32 + 2 * j + 1) * plane];
      s0 += a0 + a1; q0 += a0 * a0 + a1 * a1;
      s1 += c0 + c1; q1 += c0 * c0 + c1 * c1;
      asm("v_cvt_pk_bf16_f32 %0, %1, %2" : "=v"(w0[j]) : "v"(a0), "v"(a1));
      asm("v_cvt_pk_bf16_f32 %0, %1, %2" : "=v"(w1[j]) : "v"(c0), "v"(c1));
    }
    if (write_t) {
      const size_t o = ((((size_t)b * 2 + cc) * HIN + y) * WIN + x) * 32;
#pragma unroll
      for (int g = 0; g < 4; ++g) {
        u32x4_t v0 = {w0[4*g], w0[4*g+1], w0[4*g+2], w0[4*g+3]};
        u32x4_t v1 = {w1[4*g], w1[4*g+1], w1[4*g+2], w1[4*g+3]};
        *(u32x4_t*)(t0 + o + 8 * g) = v0;
        *(u32x4_t*)(t1 + o + 8 * g) = v1;
      }
    }
  }
  const size_t o = ((size_t)b * HIN + y) * WIN + x;
  ws[CS0_OFF + o] = s0; ws[CQ0_OFF + o] = q0;
  ws[CS1_OFF + o] = s1; ws[CQ1_OFF + o] = q1;
}

// ---------------- pass B: 3x3 boxed patch stats + norms ----------------
__global__ __launch_bounds__(512)
void boxnorm_kernel(float* __restrict__ ws) {
  const int y = blockIdx.x, b = blockIdx.y;
  const int tid = threadIdx.x;
  const float invn = 1.f / 576.f;
  const int ylo = (y > 0) ? y - 1 : 0;
  const int yhi = (y < HIN - 1) ? y + 1 : HIN - 1;
  {
    const int x = tid;
    float s = 0.f, q = 0.f;
    for (int yy = ylo; yy <= yhi; ++yy) {
      const float* rs = ws + CS0_OFF + ((size_t)b * HIN + yy) * WIN;
      const float* rq = ws + CQ0_OFF + ((size_t)b * HIN + yy) * WIN;
      const int xlo = (x > 0) ? x - 1 : 0;
      const int xhi = (x < WIN - 1) ? x + 1 : WIN - 1;
      for (int xx = xlo; xx <= xhi; ++xx) { s += rs[xx]; q += rq[xx]; }
    }
    const size_t o = ((size_t)b * HIN + y) * WIN + x;
    ws[SB0_OFF + o] = s;
    ws[LB0_OFF + o] = sqrtf(fmaxf(q - s * s * invn, 0.f));
  }
  for (int i = tid; i < 648; i += 512) {
    const int v = i - 66;
    float s = 0.f, q = 0.f;
    const int xlo = (v - 1 > 0) ? v - 1 : 0;
    const int xhi = (v + 1 < WIN - 1) ? v + 1 : WIN - 1;
    if (v + 1 >= 0 && v - 1 < WIN) {
      for (int yy = ylo; yy <= yhi; ++yy) {
        const float* rs = ws + CS1_OFF + ((size_t)b * HIN + yy) * WIN;
        const float* rq = ws + CQ1_OFF + ((size_t)b * HIN + yy) * WIN;
        for (int xx = xlo; xx <= xhi; ++xx) { s += rs[xx]; q += rq[xx]; }
      }
    }
    const size_t o = ((size_t)b * HIN + y) * 648 + i;
    ws[SB1_OFF + o] = s;
    ws[LB1_OFF + o] = sqrtf(fmaxf(q - s * s * invn, 0.f));
  }
}

// ---------------- main: 512-thread, 1 row/block, DMA depth-2, 2 blocks/CU ----------------
__global__ __launch_bounds__(512, 4)
void corrzn_dma_kernel(const float* __restrict__ ws, float* __restrict__ out) {
  __shared__ __align__(16) char smem[SMEMB];

  const int tid  = threadIdx.x;
  const int lane = tid & 63;
  const int wv   = tid >> 6;      // 0..7
  const int p    = wv & 1;        // parity
  const int chunk0 = 2 * (wv >> 1);  // 0,2,4,6
  const int lm = lane & 15;
  const int lk = lane >> 4;

  // bijective XCD-chunk swizzle over the 3072-block grid (3072 % 8 == 0)
  const int flat = blockIdx.x + 3 * (blockIdx.y + 256 * blockIdx.z);
  const int sw = (flat & 7) * 384 + (flat >> 3);
  const int bx = sw % 3;
  const int tmp = sw / 3;
  const int row = tmp & 255;
  const int b   = tmp >> 8;
  const int x0blk = bx * TX;

  const unsigned short* t0 = (const unsigned short*)(ws + STATS_FLOATS);
  const unsigned short* t1 = t0 + X1T_U16;

  f32x4_t acc0[5], acc1[5];
#pragma unroll
  for (int T = 0; T < 5; ++T) {
    acc0[T] = (f32x4_t){0.f, 0.f, 0.f, 0.f};
    acc1[T] = (f32x4_t){0.f, 0.f, 0.f, 0.f};
  }

  // 5 uniform DMA ops per wave per step (ops 0-15: x0; 16-39: x1)
  auto issue = [&](int k) {
    const int r = k >> 1, cc = k & 1;
    int orow = row + r - 1;
    orow = orow < 0 ? 0 : (orow > HIN - 1 ? HIN - 1 : orow);
    char* bb = smem + (k & 1) * BUFB;
    const size_t rowo = ((((size_t)b * 2 + cc) * HIN + orow) * (size_t)WIN) * 32;
#pragma unroll
    for (int j = 0; j < 5; ++j) {
      const int o = 5 * wv + j;
      if (o < 16) {
        const int pa = o >> 3;
        const int xb = x0blk - 1 + pa;
        const int g = fixog(o & 7, xb, 7);
        const int line = 16 * g + (lane >> 2);
        const int xg = xb + 2 * line;
        const int ss = (lane & 3) ^ ((line >> 1) & 3);
        if (xg >= 0 && xg < WIN)
          gl16(t0 + rowo + (size_t)xg * 32 + ss * 8, bb + pa * X0PARB + g * 1024);
      } else {
        const int o2 = o - 16;
        const int pb = (o2 >= 12) ? 1 : 0;
        const int xb = x0blk - 65 + pb;
        const int g = fixog(o2 - 12 * pb, xb, 11);
        const int line = 16 * g + (lane >> 2);
        const int xg = xb + 2 * line;
        const int ss = (lane & 3) ^ ((line >> 1) & 3);
        if (xg >= 0 && xg < WIN)
          gl16(t1 + rowo + (size_t)xg * 32 + ss * 8, bb + X1SEC + pb * X1PARB + g * 1024);
      }
    }
  };

  // zero-init staging so masked (out-of-image) cells read as 0 forever
  {
    u32x4_t z = {0u, 0u, 0u, 0u};
    for (int i = tid; i < 2 * BUFB / 16; i += 512)
      ((u32x4_t*)smem)[i] = z;
  }
  __syncthreads();

  issue(0); issue(1);
  WAITVM(5);
  __builtin_amdgcn_s_barrier();
  asm volatile("" ::: "memory");

  // ============ K-loop: 3 padded rows x 2 channel chunks = 6 steps ============
#pragma unroll
  for (int k = 0; k < 6; ++k) {
    const int orow = row + (k >> 1) - 1;
    if (orow >= 0 && orow < HIN) {
      char* bb = smem + (k & 1) * BUFB;
      bf16x8_t afr0, afr1;
      {
        const int pos = 16 * chunk0 + lm;
        const int slot = lk ^ ((pos >> 1) & 3);
        afr0 = *(const bf16x8_t*)(bb + p * X0PARB + pos * 64 + slot * 16);
      }
      {
        const int pos = 16 * (chunk0 + 1) + lm;
        const int slot = lk ^ ((pos >> 1) & 3);
        afr1 = *(const bf16x8_t*)(bb + p * X0PARB + pos * 64 + slot * 16);
      }
#pragma unroll
      for (int u = 0; u < 6; ++u) {
        const int pos = 16 * (chunk0 + u) + lm;
        const int slot = lk ^ ((pos >> 1) & 3);
        const bf16x8_t bfrT = *(const bf16x8_t*)(bb + X1SEC + p * X1PARB + pos * 64 + slot * 16);
        if (u <= 4)
          acc0[u] = __builtin_amdgcn_mfma_f32_16x16x32_bf16(afr0, bfrT, acc0[u], 0, 0, 0);
        if (u >= 1)
          acc1[u-1] = __builtin_amdgcn_mfma_f32_16x16x32_bf16(afr1, bfrT, acc1[u-1], 0, 0, 0);
      }
    }
    asm volatile("s_waitcnt lgkmcnt(0)" ::: "memory");
    __builtin_amdgcn_s_barrier();
    asm volatile("" ::: "memory");
    if (k == 5) break;
    if (k + 2 < 6) {
      issue(k + 2);                 // into buffer (k&1), just freed
      WAITVM(5);                    // step k+1 loads complete
    } else {
      WAITVM(0);
    }
    __builtin_amdgcn_s_barrier();
    asm volatile("" ::: "memory");
  }

  // ============ epilogue: single row, Q aliases staging ============
  float* Q   = (float*)(smem);
  float* s0x = (float*)(smem + SM_S0X);
  float* l0x = (float*)(smem + SM_L0X);
  float* s1x = (float*)(smem + SM_S1X);
  float* l1x = (float*)(smem + SM_L1X);
  const float invn = 1.f / 576.f;

  for (int i = tid; i < 254; i += 512) {
    const int x = x0blk + i;
    const size_t o = ((size_t)b * HIN + row) * WIN + x;
    s0x[i] = (x < WIN) ? ws[SB0_OFF + o] : 0.f;
    l0x[i] = (x < WIN) ? ws[LB0_OFF + o] : 0.f;
  }
  for (int j2 = tid; j2 < 382; j2 += 512) {
    const int idx = x0blk + 2 + j2;
    const size_t o = ((size_t)b * HIN + row) * 648 + idx;
    s1x[j2] = (idx < 648) ? ws[SB1_OFF + o] : 0.f;
    l1x[j2] = (idx < 648) ? ws[LB1_OFF + o] : 0.f;
  }
#pragma unroll
  for (int T = 0; T < 5; ++T)
#pragma unroll
    for (int q = 0; q < 4; ++q) {
      const int di = 16 * T + lm - 4 * lk - q;
      if (di >= 0 && di <= 64) {
        const int mg0 = 16 * chunk0 + lk * 4 + q;
        Q[di * 257 + 2 * mg0 + p] = acc0[T][q];
        const int mg1 = 16 * (chunk0 + 1) + lk * 4 + q;
        Q[di * 257 + 2 * mg1 + p] = acc1[T][q];
      }
    }
  __syncthreads();
  // output: fixed xl pair per thread, walk di (no divisions, float2 stores)
  const int xl = 2 * (tid & 127);
  const int di0 = tid >> 7;                      // 0..3
  if (xl < TX && x0blk + xl + 1 < WIN) {
    for (int di = di0; di < NDISP; di += 4) {
      const float qa0 = Q[di * 257 + xl];
      const float qa1 = Q[di * 257 + xl + 1];
      const float qa2 = Q[di * 257 + xl + 2];
      const float qa3 = Q[di * 257 + xl + 3];
      const int j = xl + 2 * di;
      const float n0 = (qa0 + qa1 + qa2) - s0x[xl] * s1x[j] * invn;
      const float d0 = l0x[xl] * l1x[j] + 1e-8f;
      const float n1 = (qa1 + qa2 + qa3) - s0x[xl + 1] * s1x[j + 1] * invn;
      const float d1 = l0x[xl + 1] * l1x[j + 1] + 1e-8f;
      float r0, r1;
      asm("v_rcp_f32 %0, %1" : "=v"(r0) : "v"(d0));
      asm("v_rcp_f32 %0, %1" : "=v"(r1) : "v"(d1));
      float2 o2; o2.x = n0 * r0; o2.y = n1 * r1;
      *(float2*)(out + (((size_t)b * NDISP + di) * HIN + row) * WIN + x0blk + xl) = o2;
    }
  }
}

// ---------------- fallback monolith (R9, 211us) ----------------
__global__ __launch_bounds__(512, 2)
void corrzn_kernel(const float* __restrict__ x0, const float* __restrict__ x1,
                   const float* __restrict__ ws, float* __restrict__ out) {
  __shared__ __align__(16) char smem[FB_SMEM];
  const int tid  = threadIdx.x;
  const int lane = tid & 63;
  const int wv   = tid >> 6;
  const int p    = wv & 1;
  const int chunk0 = 2 * (wv >> 1);
  const int lm = lane & 15;
  const int lk = lane >> 4;
  const int t5  = tid & 31;
  const int cpx = tid >> 5;
  const int x0blk = blockIdx.x * TX;
  const int y0    = blockIdx.y * TY;
  const int b     = blockIdx.z;
  const size_t plane = (size_t)HIN * WIN;
  const float* x0b = x0 + (size_t)b * CH * plane;
  const float* x1b = x1 + (size_t)b * CH * plane;

  f32x4_t acc[TY][2][5];
#pragma unroll
  for (int t = 0; t < TY; ++t)
#pragma unroll
    for (int mc = 0; mc < 2; ++mc)
#pragma unroll
      for (int T = 0; T < 5; ++T)
        acc[t][mc][T] = (f32x4_t){0.f, 0.f, 0.f, 0.f};

  float2 R0[12], R1[12];
  auto prefetch = [&](int k) {
    const int r = k >> 1, cc = k & 1;
    const int orow = y0 + r - 1;
    const bool rowok = (orow >= 0) && (orow < HIN);
    const int ro = rowok ? orow : 0;
    const float* s0p = x0b + (size_t)(cc * 32 + 2 * cpx) * plane + (size_t)ro * WIN;
    const float* s1p = x1b + (size_t)(cc * 32 + 2 * cpx) * plane + (size_t)ro * WIN;
#pragma unroll
    for (int it = 0; it < 5; ++it) {
      const int wp = 32 * it + t5;
      const int xg = x0blk - 2 + 2 * wp;
      float2 a = {0.f, 0.f}, c = {0.f, 0.f};
      if (rowok && wp <= 128 && xg >= 0 && xg < WIN - 1) {
        a = *(const float2*)(s0p + xg);
        c = *(const float2*)(s0p + plane + xg);
      }
      R0[it] = a; R1[it] = c;
    }
#pragma unroll
    for (int it = 0; it < 7; ++it) {
      const int wp = 32 * it + t5;
      const int xg = x0blk - 66 + 2 * wp;
      float2 a = {0.f, 0.f}, c = {0.f, 0.f};
      if (rowok && wp <= 192 && xg >= 0 && xg < WIN - 1) {
        a = *(const float2*)(s1p + xg);
        c = *(const float2*)(s1p + plane + xg);
      }
      R0[5 + it] = a; R1[5 + it] = c;
    }
  };
  auto wstage = [&](int bb) {
#pragma unroll
    for (int it = 0; it < 12; ++it) {
      const bool isx1 = it >= 5;
      const int wp = 32 * (isx1 ? it - 5 : it) + t5;
      const int base = bb + (isx1 ? FB_X1 : FB_X0);
      const int ps   = isx1 ? FB_X1PS : FB_X0PS;
      const int pmax = isx1 ? 192 : 128;
      u32 pkA, pkB;
      asm("v_cvt_pk_bf16_f32 %0, %1, %2" : "=v"(pkA) : "v"(R0[it].x), "v"(R1[it].x));
      asm("v_cvt_pk_bf16_f32 %0, %1, %2" : "=v"(pkB) : "v"(R0[it].y), "v"(R1[it].y));
      if (wp >= 1 && wp <= pmax) {
        const int pos = wp - 1;
        const int slot = (cpx >> 2) ^ ((pos >> 1) & 3);
        *(u32*)(smem + base + ps + pos * 64 + slot * 16 + (cpx & 3) * 4) = pkA;
      }
      if (wp <= pmax - 1) {
        const int pos = wp;
        const int slot = (cpx >> 2) ^ ((pos >> 1) & 3);
        *(u32*)(smem + base + pos * 64 + slot * 16 + (cpx & 3) * 4) = pkB;
      }
    }
  };

  prefetch(0); wstage(0); prefetch(1);
  asm volatile("s_waitcnt lgkmcnt(0)" ::: "memory");
  __builtin_amdgcn_s_barrier();
  asm volatile("" ::: "memory");

#pragma unroll
  for (int k = 0; k < 12; ++k) {
    const int r = k >> 1;
    const int cur = (k & 1) * FB_BUF;
    bf16x8_t afr[2], bfr[6];
#pragma unroll
    for (int mc = 0; mc < 2; ++mc) {
      const int pos = 16 * (chunk0 + mc) + lm;
      const int slot = lk ^ ((pos >> 1) & 3);
      afr[mc] = *(const bf16x8_t*)(smem + cur + FB_X0 + p * FB_X0PS + pos * 64 + slot * 16);
    }
#pragma unroll
    for (int u = 0; u < 6; ++u) {
      const int pos = 16 * (chunk0 + u) + lm;
      const int slot = lk ^ ((pos >> 1) & 3);
      bfr[u] = *(const bf16x8_t*)(smem + cur + FB_X1 + p * FB_X1PS + pos * 64 + slot * 16);
    }
#pragma unroll
    for (int t = 0; t < TY; ++t) {
      if (t >= r - 2 && t <= r) {
#pragma unroll
        for (int mc = 0; mc < 2; ++mc)
#pragma unroll
          for (int T = 0; T < 5; ++T)
            acc[t][mc][T] = __builtin_amdgcn_mfma_f32_16x16x32_bf16(
                afr[mc], bfr[mc + T], acc[t][mc][T], 0, 0, 0);
      }
    }
    if (k < 11) {
      wstage(((k + 1) & 1) * FB_BUF);
      if (k + 2 < 12) prefetch(k + 2);
      asm volatile("s_waitcnt lgkmcnt(0)" ::: "memory");
      __builtin_amdgcn_s_barrier();
      asm volatile("" ::: "memory");
    }
  }

  float* Q   = (float*)(smem + FB_QB);
  float* s0x = (float*)(smem + FB_S0X);
  float* l0x = (float*)(smem + FB_L0X);
  float* s1x = (float*)(smem + FB_S1X);
  float* l1x = (float*)(smem + FB_L1X);
  const float invn = 1.f / 576.f;
#pragma unroll
  for (int t = 0; t < TY; ++t) {
    const int row = y0 + t;
    __syncthreads();
    for (int i = tid; i < 254; i += 512) {
      const int x = x0blk + i;
      const size_t o = ((size_t)b * HIN + row) * WIN + x;
      s0x[i] = (x < WIN) ? ws[SB0_OFF + o] : 0.f;
      l0x[i] = (x < WIN) ? ws[LB0_OFF + o] : 0.f;
    }
    for (int j2 = tid; j2 < 382; j2 += 512) {
      const int idx = x0blk + 2 + j2;
      const size_t o = ((size_t)b * HIN + row) * 648 + idx;
      s1x[j2] = (idx < 648) ? ws[SB1_OFF + o] : 0.f;
      l1x[j2] = (idx < 648) ? ws[LB1_OFF + o] : 0.f;
    }
#pragma unroll
    for (int mc = 0; mc < 2; ++mc)
#pragma unroll
      for (int T = 0; T < 5; ++T)
#pragma unroll
        for (int q = 0; q < 4; ++q) {
          const int mg = 16 * (chunk0 + mc) + lk * 4 + q;
          const int di = 16 * T + lm - 4 * lk - q;
          if (di >= 0 && di <= 64)
            Q[di * 257 + 2 * mg + p] = acc[t][mc][T][q];
        }
    __syncthreads();
    for (int oi = tid; oi < NDISP * TX; oi += 512) {
      const int di = oi / TX;
      const int xl = oi - di * TX;
      const int x = x0blk + xl;
      if (x < WIN) {
        const float q3 = Q[di * 257 + xl] + Q[di * 257 + xl + 1] + Q[di * 257 + xl + 2];
        const int j = xl + 2 * di;
        const float numer = q3 - s0x[xl] * s1x[j] * invn;
        const float den = l0x[xl] * l1x[j] + 1e-8f;
        float rd;
        asm("v_rcp_f32 %0, %1" : "=v"(rd) : "v"(den));
        out[(((size_t)b * NDISP + di) * HIN + row) * WIN + x] = numer * rd;
      }
    }
  }
}

extern "C" void kernel_launch(void* const* d_in, const int* in_sizes, int n_in,
                              void* d_out, int out_size, void* d_ws, size_t ws_size,
                              hipStream_t stream) {
  const float* x0 = (const float*)d_in[0];
  const float* x1 = (const float*)d_in[1];
  float* out = (float*)d_out;
  float* wsf = (float*)d_ws;
  const int use_dma = (ws_size >= WS_NEED_BYTES) ? 1 : 0;

  colsum_kernel<<<dim3(HIN, BATCH), 512, 0, stream>>>(x0, x1, wsf, use_dma);
  boxnorm_kernel<<<dim3(HIN, BATCH), 512, 0, stream>>>(wsf);
  if (use_dma) {
    corrzn_dma_kernel<<<dim3(3, HIN, BATCH), 512, 0, stream>>>(wsf, out);
  } else {
    corrzn_kernel<<<dim3(3, HIN / TY, BATCH), 512, 0, stream>>>(x0, x1, wsf, out);
  }
}

// Round 14
// 203.011 us; speedup vs baseline: 1.2626x; 1.0204x over previous
//
#include <hip/hip_runtime.h>

typedef __attribute__((ext_vector_type(8))) short bf16x8_t;
typedef __attribute__((ext_vector_type(4))) float f32x4_t;
typedef __attribute__((ext_vector_type(4))) unsigned u32x4_t;
typedef unsigned int u32;

#define BATCH 4
#define CH 64
#define HIN 256
#define WIN 512
#define NDISP 65
#define TY 2
#define TX 254

// ---- workspace layout (floats unless noted) ----
#define CS0_OFF 0
#define CQ0_OFF  524288
#define CS1_OFF 1048576
#define CQ1_OFF 1572864
#define SB0_OFF 2097152
#define LB0_OFF 2621440
#define SB1_OFF 3145728
#define LB1_OFF 3809280
#define STATS_FLOATS 4472832UL
#define X1T_U16 33554432UL     // u16 offset of x1T within bf16T region
#define WS_NEED_BYTES (STATS_FLOATS*4UL + 2UL*X1T_U16*2UL)

// ---- DMA main kernel LDS: 2 x 40 KB staging buffers, Q/aux aliased ----
#define BUFB 40960             // one staging buffer: x0 16KB + x1 24KB
#define X0PARB 8192            // 128 lines x 64B per parity
#define X1SEC 16384
#define X1PARB 12288           // 192 lines x 64B per parity (12 groups)
#define SM_S0X 66824
#define SM_L0X 67848
#define SM_S1X 68872
#define SM_L1X 70408
#define SMEMB 81920            // exactly 80 KB -> 2 blocks/CU

// ---- fallback monolith LDS (R9) ----
#define FB_BUF 40960
#define FB_X0 0
#define FB_X0PS 8192
#define FB_X1 16384
#define FB_X1PS 12288
#define FB_QB 0
#define FB_S0X 66824
#define FB_L0X 67848
#define FB_S1X 68872
#define FB_L1X 70408
#define FB_SMEM 81920

#define WAITVM(n) asm volatile("s_waitcnt vmcnt(" #n ")" ::: "memory")

__device__ __forceinline__ void gl16(const void* g, void* l) {
  __builtin_amdgcn_global_load_lds(
      (const __attribute__((address_space(1))) u32*)g,
      (__attribute__((address_space(3))) u32*)l, 16, 0, 0);
}

__device__ __forceinline__ int fixog(int og, int xb, int ogmax) {
  const int xmin = xb + 32 * og;
  if (xmin + 30 < 0 || xmin >= WIN) {
    int f = (31 - xb) >> 5;
    f = f < 0 ? 0 : f;
    og = f > ogmax ? ogmax : f;
  }
  return og;
}

// ---------------- pass A: channel column sums + bf16 transpose-pack ----------------
// grid z: 0 -> x0 (writes CS0/CQ0 + t0), 1 -> x1 (writes CS1/CQ1 + t1)
__global__ __launch_bounds__(512)
void colsum_kernel(const float* __restrict__ x0, const float* __restrict__ x1,
                   float* __restrict__ ws, int write_t) {
  const int y = blockIdx.x, b = blockIdx.y, inp = blockIdx.z;
  const int x = threadIdx.x;
  const size_t plane = (size_t)HIN * WIN;
  const float* p = (inp ? x1 : x0) + (size_t)b * CH * plane + (size_t)y * WIN + x;
  unsigned short* tt = (unsigned short*)(ws + STATS_FLOATS) + (size_t)inp * X1T_U16;
  float s = 0.f, q = 0.f;
#pragma unroll
  for (int cc = 0; cc < 2; ++cc) {
    u32 w[16];
#pragma unroll
    for (int j = 0; j < 16; ++j) {
      const float a0 = p[(size_t)(cc * 32 + 2 * j) * plane];
      const float a1 = p[(size_t)(cc * 32 + 2 * j + 1) * plane];
      s += a0 + a1; q += a0 * a0 + a1 * a1;
      asm("v_cvt_pk_bf16_f32 %0, %1, %2" : "=v"(w[j]) : "v"(a0), "v"(a1));
    }
    if (write_t) {
      const size_t o = ((((size_t)b * 2 + cc) * HIN + y) * WIN + x) * 32;
#pragma unroll
      for (int g = 0; g < 4; ++g) {
        u32x4_t v = {w[4*g], w[4*g+1], w[4*g+2], w[4*g+3]};
        *(u32x4_t*)(tt + o + 8 * g) = v;
      }
    }
  }
  const size_t o = ((size_t)b * HIN + y) * WIN + x;
  ws[(inp ? CS1_OFF : CS0_OFF) + o] = s;
  ws[(inp ? CQ1_OFF : CQ0_OFF) + o] = q;
}

// ---------------- pass B: 3x3 boxed patch stats + norms ----------------
__global__ __launch_bounds__(512)
void boxnorm_kernel(float* __restrict__ ws) {
  const int y = blockIdx.x, b = blockIdx.y;
  const int tid = threadIdx.x;
  const float invn = 1.f / 576.f;
  const int ylo = (y > 0) ? y - 1 : 0;
  const int yhi = (y < HIN - 1) ? y + 1 : HIN - 1;
  {
    const int x = tid;
    float s = 0.f, q = 0.f;
    for (int yy = ylo; yy <= yhi; ++yy) {
      const float* rs = ws + CS0_OFF + ((size_t)b * HIN + yy) * WIN;
      const float* rq = ws + CQ0_OFF + ((size_t)b * HIN + yy) * WIN;
      const int xlo = (x > 0) ? x - 1 : 0;
      const int xhi = (x < WIN - 1) ? x + 1 : WIN - 1;
      for (int xx = xlo; xx <= xhi; ++xx) { s += rs[xx]; q += rq[xx]; }
    }
    const size_t o = ((size_t)b * HIN + y) * WIN + x;
    ws[SB0_OFF + o] = s;
    ws[LB0_OFF + o] = sqrtf(fmaxf(q - s * s * invn, 0.f));
  }
  for (int i = tid; i < 648; i += 512) {
    const int v = i - 66;
    float s = 0.f, q = 0.f;
    const int xlo = (v - 1 > 0) ? v - 1 : 0;
    const int xhi = (v + 1 < WIN - 1) ? v + 1 : WIN - 1;
    if (v + 1 >= 0 && v - 1 < WIN) {
      for (int yy = ylo; yy <= yhi; ++yy) {
        const float* rs = ws + CS1_OFF + ((size_t)b * HIN + yy) * WIN;
        const float* rq = ws + CQ1_OFF + ((size_t)b * HIN + yy) * WIN;
        for (int xx = xlo; xx <= xhi; ++xx) { s += rs[xx]; q += rq[xx]; }
      }
    }
    const size_t o = ((size_t)b * HIN + y) * 648 + i;
    ws[SB1_OFF + o] = s;
    ws[LB1_OFF + o] = sqrtf(fmaxf(q - s * s * invn, 0.f));
  }
}

// ---------------- main: 512-thread, 1 row/block, DMA depth-2, 2 blocks/CU ----------------
__global__ __launch_bounds__(512, 4)
void corrzn_dma_kernel(const float* __restrict__ ws, float* __restrict__ out) {
  __shared__ __align__(16) char smem[SMEMB];

  const int tid  = threadIdx.x;
  const int lane = tid & 63;
  const int wv   = tid >> 6;      // 0..7
  const int p    = wv & 1;        // parity
  const int chunk0 = 2 * (wv >> 1);  // 0,2,4,6
  const int lm = lane & 15;
  const int lk = lane >> 4;

  // bijective XCD-chunk swizzle over the 3072-block grid (3072 % 8 == 0)
  const int flat = blockIdx.x + 3 * (blockIdx.y + 256 * blockIdx.z);
  const int sw = (flat & 7) * 384 + (flat >> 3);
  const int bx = sw % 3;
  const int tmp = sw / 3;
  const int row = tmp & 255;
  const int b   = tmp >> 8;
  const int x0blk = bx * TX;

  const unsigned short* t0 = (const unsigned short*)(ws + STATS_FLOATS);
  const unsigned short* t1 = t0 + X1T_U16;

  f32x4_t acc0[5], acc1[5];
#pragma unroll
  for (int T = 0; T < 5; ++T) {
    acc0[T] = (f32x4_t){0.f, 0.f, 0.f, 0.f};
    acc1[T] = (f32x4_t){0.f, 0.f, 0.f, 0.f};
  }

  // 5 uniform DMA ops per wave per step (ops 0-15: x0; 16-39: x1)
  auto issue = [&](int k) {
    const int r = k >> 1, cc = k & 1;
    int orow = row + r - 1;
    orow = orow < 0 ? 0 : (orow > HIN - 1 ? HIN - 1 : orow);
    char* bb = smem + (k & 1) * BUFB;
    const size_t rowo = ((((size_t)b * 2 + cc) * HIN + orow) * (size_t)WIN) * 32;
#pragma unroll
    for (int j = 0; j < 5; ++j) {
      const int o = 5 * wv + j;
      if (o < 16) {
        const int pa = o >> 3;
        const int xb = x0blk - 1 + pa;
        const int g = fixog(o & 7, xb, 7);
        const int line = 16 * g + (lane >> 2);
        const int xg = xb + 2 * line;
        const int ss = (lane & 3) ^ ((line >> 1) & 3);
        if (xg >= 0 && xg < WIN)
          gl16(t0 + rowo + (size_t)xg * 32 + ss * 8, bb + pa * X0PARB + g * 1024);
      } else {
        const int o2 = o - 16;
        const int pb = (o2 >= 12) ? 1 : 0;
        const int xb = x0blk - 65 + pb;
        const int g = fixog(o2 - 12 * pb, xb, 11);
        const int line = 16 * g + (lane >> 2);
        const int xg = xb + 2 * line;
        const int ss = (lane & 3) ^ ((line >> 1) & 3);
        if (xg >= 0 && xg < WIN)
          gl16(t1 + rowo + (size_t)xg * 32 + ss * 8, bb + X1SEC + pb * X1PARB + g * 1024);
      }
    }
  };

  // zero-init staging so masked (out-of-image) cells read as 0 forever
  {
    u32x4_t z = {0u, 0u, 0u, 0u};
    for (int i = tid; i < 2 * BUFB / 16; i += 512)
      ((u32x4_t*)smem)[i] = z;
  }
  __syncthreads();

  issue(0); issue(1);
  WAITVM(5);
  __builtin_amdgcn_s_barrier();
  asm volatile("" ::: "memory");

  // ============ K-loop: 3 padded rows x 2 channel chunks = 6 steps ============
#pragma unroll
  for (int k = 0; k < 6; ++k) {
    const int orow = row + (k >> 1) - 1;
    if (orow >= 0 && orow < HIN) {
      char* bb = smem + (k & 1) * BUFB;
      bf16x8_t afr0, afr1;
      {
        const int pos = 16 * chunk0 + lm;
        const int slot = lk ^ ((pos >> 1) & 3);
        afr0 = *(const bf16x8_t*)(bb + p * X0PARB + pos * 64 + slot * 16);
      }
      {
        const int pos = 16 * (chunk0 + 1) + lm;
        const int slot = lk ^ ((pos >> 1) & 3);
        afr1 = *(const bf16x8_t*)(bb + p * X0PARB + pos * 64 + slot * 16);
      }
#pragma unroll
      for (int u = 0; u < 6; ++u) {
        const int pos = 16 * (chunk0 + u) + lm;
        const int slot = lk ^ ((pos >> 1) & 3);
        const bf16x8_t bfrT = *(const bf16x8_t*)(bb + X1SEC + p * X1PARB + pos * 64 + slot * 16);
        if (u <= 4)
          acc0[u] = __builtin_amdgcn_mfma_f32_16x16x32_bf16(afr0, bfrT, acc0[u], 0, 0, 0);
        if (u >= 1)
          acc1[u-1] = __builtin_amdgcn_mfma_f32_16x16x32_bf16(afr1, bfrT, acc1[u-1], 0, 0, 0);
      }
    }
    asm volatile("s_waitcnt lgkmcnt(0)" ::: "memory");
    __builtin_amdgcn_s_barrier();
    asm volatile("" ::: "memory");
    if (k == 5) break;
    if (k + 2 < 6) {
      issue(k + 2);                 // into buffer (k&1), just freed
      WAITVM(5);                    // step k+1 loads complete
    } else {
      WAITVM(0);
    }
    __builtin_amdgcn_s_barrier();
    asm volatile("" ::: "memory");
  }

  // ============ epilogue: single row, Q aliases staging ============
  float* Q   = (float*)(smem);
  float* s0x = (float*)(smem + SM_S0X);
  float* l0x = (float*)(smem + SM_L0X);
  float* s1x = (float*)(smem + SM_S1X);
  float* l1x = (float*)(smem + SM_L1X);
  const float invn = 1.f / 576.f;

  for (int i = tid; i < 254; i += 512) {
    const int x = x0blk + i;
    const size_t o = ((size_t)b * HIN + row) * WIN + x;
    s0x[i] = (x < WIN) ? ws[SB0_OFF + o] : 0.f;
    l0x[i] = (x < WIN) ? ws[LB0_OFF + o] : 0.f;
  }
  for (int j2 = tid; j2 < 382; j2 += 512) {
    const int idx = x0blk + 2 + j2;
    const size_t o = ((size_t)b * HIN + row) * 648 + idx;
    s1x[j2] = (idx < 648) ? ws[SB1_OFF + o] : 0.f;
    l1x[j2] = (idx < 648) ? ws[LB1_OFF + o] : 0.f;
  }
#pragma unroll
  for (int T = 0; T < 5; ++T)
#pragma unroll
    for (int q = 0; q < 4; ++q) {
      const int di = 16 * T + lm - 4 * lk - q;
      if (di >= 0 && di <= 64) {
        const int mg0 = 16 * chunk0 + lk * 4 + q;
        Q[di * 257 + 2 * mg0 + p] = acc0[T][q];
        const int mg1 = 16 * (chunk0 + 1) + lk * 4 + q;
        Q[di * 257 + 2 * mg1 + p] = acc1[T][q];
      }
    }
  __syncthreads();
  // output: fixed xl pair per thread, walk di (no divisions, float2 stores)
  const int xl = 2 * (tid & 127);
  const int di0 = tid >> 7;                      // 0..3
  if (xl < TX && x0blk + xl + 1 < WIN) {
    for (int di = di0; di < NDISP; di += 4) {
      const float qa0 = Q[di * 257 + xl];
      const float qa1 = Q[di * 257 + xl + 1];
      const float qa2 = Q[di * 257 + xl + 2];
      const float qa3 = Q[di * 257 + xl + 3];
      const int j = xl + 2 * di;
      const float n0 = (qa0 + qa1 + qa2) - s0x[xl] * s1x[j] * invn;
      const float d0 = l0x[xl] * l1x[j] + 1e-8f;
      const float n1 = (qa1 + qa2 + qa3) - s0x[xl + 1] * s1x[j + 1] * invn;
      const float d1 = l0x[xl + 1] * l1x[j + 1] + 1e-8f;
      float r0, r1;
      asm("v_rcp_f32 %0, %1" : "=v"(r0) : "v"(d0));
      asm("v_rcp_f32 %0, %1" : "=v"(r1) : "v"(d1));
      float2 o2; o2.x = n0 * r0; o2.y = n1 * r1;
      *(float2*)(out + (((size_t)b * NDISP + di) * HIN + row) * WIN + x0blk + xl) = o2;
    }
  }
}

// ---------------- fallback monolith (R9, 211us) ----------------
__global__ __launch_bounds__(512, 2)
void corrzn_kernel(const float* __restrict__ x0, const float* __restrict__ x1,
                   const float* __restrict__ ws, float* __restrict__ out) {
  __shared__ __align__(16) char smem[FB_SMEM];
  const int tid  = threadIdx.x;
  const int lane = tid & 63;
  const int wv   = tid >> 6;
  const int p    = wv & 1;
  const int chunk0 = 2 * (wv >> 1);
  const int lm = lane & 15;
  const int lk = lane >> 4;
  const int t5  = tid & 31;
  const int cpx = tid >> 5;
  const int x0blk = blockIdx.x * TX;
  const int y0    = blockIdx.y * TY;
  const int b     = blockIdx.z;
  const size_t plane = (size_t)HIN * WIN;
  const float* x0b = x0 + (size_t)b * CH * plane;
  const float* x1b = x1 + (size_t)b * CH * plane;

  f32x4_t acc[TY][2][5];
#pragma unroll
  for (int t = 0; t < TY; ++t)
#pragma unroll
    for (int mc = 0; mc < 2; ++mc)
#pragma unroll
      for (int T = 0; T < 5; ++T)
        acc[t][mc][T] = (f32x4_t){0.f, 0.f, 0.f, 0.f};

  float2 R0[12], R1[12];
  auto prefetch = [&](int k) {
    const int r = k >> 1, cc = k & 1;
    const int orow = y0 + r - 1;
    const bool rowok = (orow >= 0) && (orow < HIN);
    const int ro = rowok ? orow : 0;
    const float* s0p = x0b + (size_t)(cc * 32 + 2 * cpx) * plane + (size_t)ro * WIN;
    const float* s1p = x1b + (size_t)(cc * 32 + 2 * cpx) * plane + (size_t)ro * WIN;
#pragma unroll
    for (int it = 0; it < 5; ++it) {
      const int wp = 32 * it + t5;
      const int xg = x0blk - 2 + 2 * wp;
      float2 a = {0.f, 0.f}, c = {0.f, 0.f};
      if (rowok && wp <= 128 && xg >= 0 && xg < WIN - 1) {
        a = *(const float2*)(s0p + xg);
        c = *(const float2*)(s0p + plane + xg);
      }
      R0[it] = a; R1[it] = c;
    }
#pragma unroll
    for (int it = 0; it < 7; ++it) {
      const int wp = 32 * it + t5;
      const int xg = x0blk - 66 + 2 * wp;
      float2 a = {0.f, 0.f}, c = {0.f, 0.f};
      if (rowok && wp <= 192 && xg >= 0 && xg < WIN - 1) {
        a = *(const float2*)(s1p + xg);
        c = *(const float2*)(s1p + plane + xg);
      }
      R0[5 + it] = a; R1[5 + it] = c;
    }
  };
  auto wstage = [&](int bb) {
#pragma unroll
    for (int it = 0; it < 12; ++it) {
      const bool isx1 = it >= 5;
      const int wp = 32 * (isx1 ? it - 5 : it) + t5;
      const int base = bb + (isx1 ? FB_X1 : FB_X0);
      const int ps   = isx1 ? FB_X1PS : FB_X0PS;
      const int pmax = isx1 ? 192 : 128;
      u32 pkA, pkB;
      asm("v_cvt_pk_bf16_f32 %0, %1, %2" : "=v"(pkA) : "v"(R0[it].x), "v"(R1[it].x));
      asm("v_cvt_pk_bf16_f32 %0, %1, %2" : "=v"(pkB) : "v"(R0[it].y), "v"(R1[it].y));
      if (wp >= 1 && wp <= pmax) {
        const int pos = wp - 1;
        const int slot = (cpx >> 2) ^ ((pos >> 1) & 3);
        *(u32*)(smem + base + ps + pos * 64 + slot * 16 + (cpx & 3) * 4) = pkA;
      }
      if (wp <= pmax - 1) {
        const int pos = wp;
        const int slot = (cpx >> 2) ^ ((pos >> 1) & 3);
        *(u32*)(smem + base + pos * 64 + slot * 16 + (cpx & 3) * 4) = pkB;
      }
    }
  };

  prefetch(0); wstage(0); prefetch(1);
  asm volatile("s_waitcnt lgkmcnt(0)" ::: "memory");
  __builtin_amdgcn_s_barrier();
  asm volatile("" ::: "memory");

#pragma unroll
  for (int k = 0; k < 12; ++k) {
    const int r = k >> 1;
    const int cur = (k & 1) * FB_BUF;
    bf16x8_t afr[2], bfr[6];
#pragma unroll
    for (int mc = 0; mc < 2; ++mc) {
      const int pos = 16 * (chunk0 + mc) + lm;
      const int slot = lk ^ ((pos >> 1) & 3);
      afr[mc] = *(const bf16x8_t*)(smem + cur + FB_X0 + p * FB_X0PS + pos * 64 + slot * 16);
    }
#pragma unroll
    for (int u = 0; u < 6; ++u) {
      const int pos = 16 * (chunk0 + u) + lm;
      const int slot = lk ^ ((pos >> 1) & 3);
      bfr[u] = *(const bf16x8_t*)(smem + cur + FB_X1 + p * FB_X1PS + pos * 64 + slot * 16);
    }
#pragma unroll
    for (int t = 0; t < TY; ++t) {
      if (t >= r - 2 && t <= r) {
#pragma unroll
        for (int mc = 0; mc < 2; ++mc)
#pragma unroll
          for (int T = 0; T < 5; ++T)
            acc[t][mc][T] = __builtin_amdgcn_mfma_f32_16x16x32_bf16(
                afr[mc], bfr[mc + T], acc[t][mc][T], 0, 0, 0);
      }
    }
    if (k < 11) {
      wstage(((k + 1) & 1) * FB_BUF);
      if (k + 2 < 12) prefetch(k + 2);
      asm volatile("s_waitcnt lgkmcnt(0)" ::: "memory");
      __builtin_amdgcn_s_barrier();
      asm volatile("" ::: "memory");
    }
  }

  float* Q   = (float*)(smem + FB_QB);
  float* s0x = (float*)(smem + FB_S0X);
  float* l0x = (float*)(smem + FB_L0X);
  float* s1x = (float*)(smem + FB_S1X);
  float* l1x = (float*)(smem + FB_L1X);
  const float invn = 1.f / 576.f;
#pragma unroll
  for (int t = 0; t < TY; ++t) {
    const int row = y0 + t;
    __syncthreads();
    for (int i = tid; i < 254; i += 512) {
      const int x = x0blk + i;
      const size_t o = ((size_t)b * HIN + row) * WIN + x;
      s0x[i] = (x < WIN) ? ws[SB0_OFF + o] : 0.f;
      l0x[i] = (x < WIN) ? ws[LB0_OFF + o] : 0.f;
    }
    for (int j2 = tid; j2 < 382; j2 += 512) {
      const int idx = x0blk + 2 + j2;
      const size_t o = ((size_t)b * HIN + row) * 648 + idx;
      s1x[j2] = (idx < 648) ? ws[SB1_OFF + o] : 0.f;
      l1x[j2] = (idx < 648) ? ws[LB1_OFF + o] : 0.f;
    }
#pragma unroll
    for (int mc = 0; mc < 2; ++mc)
#pragma unroll
      for (int T = 0; T < 5; ++T)
#pragma unroll
        for (int q = 0; q < 4; ++q) {
          const int mg = 16 * (chunk0 + mc) + lk * 4 + q;
          const int di = 16 * T + lm - 4 * lk - q;
          if (di >= 0 && di <= 64)
            Q[di * 257 + 2 * mg + p] = acc[t][mc][T][q];
        }
    __syncthreads();
    for (int oi = tid; oi < NDISP * TX; oi += 512) {
      const int di = oi / TX;
      const int xl = oi - di * TX;
      const int x = x0blk + xl;
      if (x < WIN) {
        const float q3 = Q[di * 257 + xl] + Q[di * 257 + xl + 1] + Q[di * 257 + xl + 2];
        const int j = xl + 2 * di;
        const float numer = q3 - s0x[xl] * s1x[j] * invn;
        const float den = l0x[xl] * l1x[j] + 1e-8f;
        float rd;
        asm("v_rcp_f32 %0, %1" : "=v"(rd) : "v"(den));
        out[(((size_t)b * NDISP + di) * HIN + row) * WIN + x] = numer * rd;
      }
    }
  }
}

extern "C" void kernel_launch(void* const* d_in, const int* in_sizes, int n_in,
                              void* d_out, int out_size, void* d_ws, size_t ws_size,
                              hipStream_t stream) {
  const float* x0 = (const float*)d_in[0];
  const float* x1 = (const float*)d_in[1];
  float* out = (float*)d_out;
  float* wsf = (float*)d_ws;
  const int use_dma = (ws_size >= WS_NEED_BYTES) ? 1 : 0;

  colsum_kernel<<<dim3(HIN, BATCH, 2), 512, 0, stream>>>(x0, x1, wsf, use_dma);
  boxnorm_kernel<<<dim3(HIN, BATCH), 512, 0, stream>>>(wsf);
  if (use_dma) {
    corrzn_dma_kernel<<<dim3(3, HIN, BATCH), 512, 0, stream>>>(wsf, out);
  } else {
    corrzn_kernel<<<dim3(3, HIN / TY, BATCH), 512, 0, stream>>>(x0, x1, wsf, out);
  }
}